// Round 8
// baseline (230.701 us; speedup 1.0000x reference)
//
#include <hip/hip_runtime.h>
#include <hip/hip_bf16.h>
#include <math.h>

#define EMBED 1024
#define HEADS 16
#define HDIM 64
#define T_SEQ 4096

typedef __bf16 bf16;
typedef bf16 bf16x8 __attribute__((ext_vector_type(8)));
typedef float f32x4 __attribute__((ext_vector_type(4)));
typedef float f32x16 __attribute__((ext_vector_type(16)));

// async global->LDS, 16B per lane; LDS dest = wave-uniform base + lane*16.
#define GL(gp, lp)                                                            \
  __builtin_amdgcn_global_load_lds(                                           \
      (const __attribute__((address_space(1))) void*)(gp),                    \
      (__attribute__((address_space(3))) void*)(lp), 16, 0, 0)

// hardware 2^x
__device__ __forceinline__ float fexp2(float x) {
  float r;
  asm("v_exp_f32 %0, %1" : "=v"(r) : "v"(x));
  return r;
}

// ---------------------------------------------------------------------------
// fp32 -> bf16 elementwise (n % 8 == 0)
// ---------------------------------------------------------------------------
__global__ __launch_bounds__(256) void f32_to_bf16(
    const float* __restrict__ in, bf16* __restrict__ out, int n) {
  int i = (blockIdx.x * 256 + threadIdx.x) * 8;
  if (i >= n) return;
  float4 a = *(const float4*)&in[i];
  float4 b = *(const float4*)&in[i + 4];
  bf16x8 o;
  o[0] = (bf16)a.x; o[1] = (bf16)a.y; o[2] = (bf16)a.z; o[3] = (bf16)a.w;
  o[4] = (bf16)b.x; o[5] = (bf16)b.y; o[6] = (bf16)b.z; o[7] = (bf16)b.w;
  *(bf16x8*)&out[i] = o;
}

// ---------------------------------------------------------------------------
// Transpose fp32 [rows][cols] -> bf16 [cols][rows].
// ---------------------------------------------------------------------------
__global__ __launch_bounds__(256) void transpose_f32_bf16(
    const float* __restrict__ in, bf16* __restrict__ out, int rows, int cols) {
  __shared__ bf16 t[32][33];
  const int c0 = blockIdx.x * 32, r0 = blockIdx.y * 32;
  const int tx = threadIdx.x & 31, ty = threadIdx.x >> 5;
#pragma unroll
  for (int i = 0; i < 4; ++i)
    t[ty + 8 * i][tx] = (bf16)in[(size_t)(r0 + ty + 8 * i) * cols + c0 + tx];
  __syncthreads();
#pragma unroll
  for (int i = 0; i < 4; ++i)
    out[(size_t)(c0 + ty + 8 * i) * rows + r0 + tx] = t[tx][ty + 8 * i];
}

// ---------------------------------------------------------------------------
// Transpose V part of qkv into vT [H*64][T].
// ---------------------------------------------------------------------------
__global__ __launch_bounds__(256) void transpose_v(
    const bf16* __restrict__ qkvb, bf16* __restrict__ vT) {
  __shared__ bf16 t[64][65];
  const int h = blockIdx.y;
  const int t0 = blockIdx.x * 64;
  const int tx = threadIdx.x & 63, ty = threadIdx.x >> 6;
#pragma unroll
  for (int i = 0; i < 16; ++i)
    t[ty + 4 * i][tx] =
        qkvb[(size_t)(t0 + ty + 4 * i) * (3 * EMBED) + 2 * EMBED + h * HDIM + tx];
  __syncthreads();
#pragma unroll
  for (int i = 0; i < 16; ++i)
    vT[((size_t)h * HDIM + ty + 4 * i) * T_SEQ + t0 + tx] = t[tx][ty + 4 * i];
}

// ---------------------------------------------------------------------------
// bf16 MFMA GEMM:  C[M][N] = A[M][K] @ BT[N][K]^T + bias[N]
// 128x128 tile, BK=32, 4 waves. global_load_lds staging, double-buffered,
// T4 counted vmcnt: raw s_barrier, prefetch stays in flight (never vmcnt(0)
// in the main loop).
// ---------------------------------------------------------------------------
template <bool OUT_F32>
__global__ __launch_bounds__(256) void gemm_bt_bias(
    const bf16* __restrict__ A, const bf16* __restrict__ BT,
    const float* __restrict__ bias, void* __restrict__ Cout,
    int M, int N, int K) {
  __shared__ __align__(16) bf16 As[2][128 * 32];
  __shared__ __align__(16) bf16 Bs[2][128 * 32];
  const int tid = threadIdx.x;
  const int lane = tid & 63;
  const int w = tid >> 6;
  const int wr = w >> 1, wc = w & 1;
  const int l16 = lane & 15, lq = lane >> 4;
  const int brow = blockIdx.y * 128;
  const int bcol = blockIdx.x * 128;

  // staging: wave w covers rows [w*32, w*32+32) in two 16-row chunks.
  // lane l: row = chunk + (l>>2), 16B slot = l&3 (matches linear LDS order)
  const int strow = w * 32 + (lane >> 2);
  const int stsl = (lane & 3) * 8;
  const bf16* Abase = A + (size_t)(brow + strow) * K + stsl;
  const bf16* Bbase = BT + (size_t)(bcol + strow) * K + stsl;

#define STAGE_G(buf, k0)                                        \
  {                                                             \
    GL(Abase + (k0), &As[buf][(w * 32) * 32]);                  \
    GL(Abase + (k0) + 16 * K, &As[buf][(w * 32 + 16) * 32]);    \
    GL(Bbase + (k0), &Bs[buf][(w * 32) * 32]);                  \
    GL(Bbase + (k0) + 16 * K, &Bs[buf][(w * 32 + 16) * 32]);    \
  }

  f32x4 acc[4][4] = {};
  const int NIT = K / 32;

  STAGE_G(0, 0);
  for (int it = 0; it < NIT; ++it) {
    const int cur = it & 1;
    if (it + 1 < NIT) {
      STAGE_G(cur ^ 1, (it + 1) * 32);               // prefetch: 4 loads
      asm volatile("s_waitcnt vmcnt(4)" ::: "memory");  // wait only cur's 4
    } else {
      asm volatile("s_waitcnt vmcnt(0)" ::: "memory");  // last: drain
    }
    __builtin_amdgcn_s_barrier();  // all waves: buf cur fully staged

    bf16x8 af[4], bfr[4];
#pragma unroll
    for (int m = 0; m < 4; ++m)
      af[m] = *(const bf16x8*)&As[cur][(wr * 64 + m * 16 + l16) * 32 + lq * 8];
#pragma unroll
    for (int n = 0; n < 4; ++n)
      bfr[n] = *(const bf16x8*)&Bs[cur][(wc * 64 + n * 16 + l16) * 32 + lq * 8];
#pragma unroll
    for (int m = 0; m < 4; ++m)
#pragma unroll
      for (int n = 0; n < 4; ++n)
        acc[m][n] =
            __builtin_amdgcn_mfma_f32_16x16x32_bf16(af[m], bfr[n], acc[m][n], 0, 0, 0);

    __builtin_amdgcn_s_barrier();  // reads of buf cur done -> next iter may overwrite
  }
#undef STAGE_G

#pragma unroll
  for (int m = 0; m < 4; ++m) {
    const int row = brow + wr * 64 + m * 16 + lq * 4;
#pragma unroll
    for (int n = 0; n < 4; ++n) {
      const int col = bcol + wc * 64 + n * 16 + l16;
      const float bv = bias[col];
#pragma unroll
      for (int r2 = 0; r2 < 4; ++r2) {
        float v = acc[m][n][r2] + bv;
        if (OUT_F32)
          ((float*)Cout)[(size_t)(row + r2) * N + col] = v;
        else
          ((bf16*)Cout)[(size_t)(row + r2) * N + col] = (bf16)v;
      }
    }
  }
}

// ---------------------------------------------------------------------------
// cvt_pk + permlane32_swap packing helper.
// ---------------------------------------------------------------------------
__device__ __forceinline__ bf16x8 pk_swap8(float a0, float a1, float a2, float a3,
                                           float a4, float a5, float a6, float a7) {
  unsigned W0, W1, W2, W3;
  asm("v_cvt_pk_bf16_f32 %0, %1, %2" : "=v"(W0) : "v"(a0), "v"(a1));
  asm("v_cvt_pk_bf16_f32 %0, %1, %2" : "=v"(W1) : "v"(a2), "v"(a3));
  asm("v_cvt_pk_bf16_f32 %0, %1, %2" : "=v"(W2) : "v"(a4), "v"(a5));
  asm("v_cvt_pk_bf16_f32 %0, %1, %2" : "=v"(W3) : "v"(a6), "v"(a7));
  asm("v_permlane32_swap_b32 %0, %1" : "+v"(W0), "+v"(W2));
  asm("v_permlane32_swap_b32 %0, %1" : "+v"(W1), "+v"(W3));
  union { unsigned u[4]; bf16x8 v; } r;
  r.u[0] = W0; r.u[1] = W1; r.u[2] = W2; r.u[3] = W3;
  return r.v;
}

// ---------------------------------------------------------------------------
// Flash attention, swapped layout, exp2 domain, KV-split jobs (as round 6),
// ZERO LDS / ZERO barriers: K and V A-fragments loaded directly from global
// (16B/lane dwordx4; KV is L1/L2-resident). Waves fully independent.
// A-frag layout (32x32x16): lane l -> row = l&31, k = chunk*16 + (l>>5)*8 + j.
// ---------------------------------------------------------------------------
__global__ __launch_bounds__(256) void flash_attn_mfma(
    const bf16* __restrict__ qkvb, const bf16* __restrict__ vT,
    bf16* __restrict__ out, bf16* __restrict__ partO_main,
    bf16* __restrict__ partO_ovf, float2* __restrict__ partML) {
  const int h = blockIdx.y;
  const int job = 79 - (int)blockIdx.x;  // big jobs first
  int qtb, np, part;
  if (job < 8)       { qtb = job;                np = 1; part = 0; }
  else if (job < 24) { qtb = 8 + ((job - 8) >> 1);  np = 2; part = (job - 8) & 1; }
  else if (job < 48) { int t = job - 24; qtb = 16 + t / 3; np = 3; part = t - (t / 3) * 3; }
  else               { int t = job - 48; qtb = 24 + (t >> 2); np = 4; part = t & 3; }
  const int nt = 2 * qtb + 2;
  const int bsz = nt / np, rem = nt % np;
  const int k0t = part * bsz + min(part, rem);
  const int k1t = k0t + bsz + (part < rem ? 1 : 0);

  int lslot = -1;
  if (np > 1) {
    if (qtb < 16)      lslot = (qtb - 8) * 2 + part;
    else if (qtb < 24) lslot = 16 + (qtb - 16) * 3 + part;
    else               lslot = 40 + (qtb - 24) * 4 + part;
  }

  const int q0 = qtb * 128;
  const int tid = threadIdx.x;
  const int lane = tid & 63;
  const int w = tid >> 6;
  const int qi = lane & 31;   // q (and A-frag row) index
  const int hi = lane >> 5;   // k-half selector

  const int qrow = q0 + w * 32 + qi;

  // Q B-fragments, pre-scaled by 0.125*log2(e) (exp2-domain softmax)
  const float QSCALE = 0.1803368867f;
  bf16x8 qb0, qb1, qb2, qb3;
  {
    const bf16* qp = &qkvb[(size_t)qrow * (3 * EMBED) + h * HDIM + hi * 8];
    qb0 = *(const bf16x8*)(qp + 0);
    qb1 = *(const bf16x8*)(qp + 16);
    qb2 = *(const bf16x8*)(qp + 32);
    qb3 = *(const bf16x8*)(qp + 48);
#pragma unroll
    for (int j = 0; j < 8; ++j) {
      qb0[j] = (bf16)((float)qb0[j] * QSCALE);
      qb1[j] = (bf16)((float)qb1[j] * QSCALE);
      qb2[j] = (bf16)((float)qb2[j] * QSCALE);
      qb3[j] = (bf16)((float)qb3[j] * QSCALE);
    }
  }

  f32x16 oA = {}, oB = {};
  float m_r = -INFINITY, l_r = 0.f;

  // per-tile global A-frag bases (advance by kt inside loop)
  const bf16* kbase = qkvb + (size_t)qi * (3 * EMBED) + EMBED + h * HDIM + hi * 8;
  const bf16* vbase = vT + ((size_t)h * HDIM + qi) * T_SEQ + hi * 8;

  for (int kt = k0t; kt < k1t; ++kt) {
    // tiles are increasing; once fully masked for this wave, we're done
    if (kt * 64 > q0 + w * 32 + 31) break;

    const bf16* kb = kbase + (size_t)(kt * 64) * (3 * EMBED);
    const bf16* kb2 = kb + (size_t)32 * (3 * EMBED);
    const bf16* vb = vbase + kt * 64;
    const bf16* vb2 = vb + (size_t)32 * T_SEQ;

    // K fragments (keys 0-31 / 32-63, k-chunks c*16)
    bf16x8 kA0 = *(const bf16x8*)(kb + 0);
    bf16x8 kA1 = *(const bf16x8*)(kb + 16);
    bf16x8 kA2 = *(const bf16x8*)(kb + 32);
    bf16x8 kA3 = *(const bf16x8*)(kb + 48);
    bf16x8 kB0 = *(const bf16x8*)(kb2 + 0);
    bf16x8 kB1 = *(const bf16x8*)(kb2 + 16);
    bf16x8 kB2 = *(const bf16x8*)(kb2 + 32);
    bf16x8 kB3 = *(const bf16x8*)(kb2 + 48);
    // V^T fragments (d 0-31 / 32-63 rows, key-chunks c*16)
    bf16x8 vA0 = *(const bf16x8*)(vb + 0);
    bf16x8 vA1 = *(const bf16x8*)(vb + 16);
    bf16x8 vA2 = *(const bf16x8*)(vb + 32);
    bf16x8 vA3 = *(const bf16x8*)(vb + 48);
    bf16x8 vB0 = *(const bf16x8*)(vb2 + 0);
    bf16x8 vB1 = *(const bf16x8*)(vb2 + 16);
    bf16x8 vB2 = *(const bf16x8*)(vb2 + 32);
    bf16x8 vB3 = *(const bf16x8*)(vb2 + 48);

    // ---- S^T = mfma(K, Q) ----
    f32x16 sA = {}, sB = {};
    __builtin_amdgcn_s_setprio(1);
    sA = __builtin_amdgcn_mfma_f32_32x32x16_bf16(kA0, qb0, sA, 0, 0, 0);
    sB = __builtin_amdgcn_mfma_f32_32x32x16_bf16(kB0, qb0, sB, 0, 0, 0);
    sA = __builtin_amdgcn_mfma_f32_32x32x16_bf16(kA1, qb1, sA, 0, 0, 0);
    sB = __builtin_amdgcn_mfma_f32_32x32x16_bf16(kB1, qb1, sB, 0, 0, 0);
    sA = __builtin_amdgcn_mfma_f32_32x32x16_bf16(kA2, qb2, sA, 0, 0, 0);
    sB = __builtin_amdgcn_mfma_f32_32x32x16_bf16(kB2, qb2, sB, 0, 0, 0);
    sA = __builtin_amdgcn_mfma_f32_32x32x16_bf16(kA3, qb3, sA, 0, 0, 0);
    sB = __builtin_amdgcn_mfma_f32_32x32x16_bf16(kB3, qb3, sB, 0, 0, 0);
    __builtin_amdgcn_s_setprio(0);

    // ---- causal mask (only near the diagonal) ----
    if (kt * 64 + 63 > q0 + w * 32) {
      const int qg = qrow;
#pragma unroll
      for (int r = 0; r < 16; ++r) {
        const int kl = (r & 3) + 8 * (r >> 2) + 4 * hi;
        if (kt * 64 + kl > qg) sA[r] = -INFINITY;
        if (kt * 64 + 32 + kl > qg) sB[r] = -INFINITY;
      }
    }

    // ---- online softmax (exp2 domain): tree max, defer-max, exp, tree sum
    float tm[16];
#pragma unroll
    for (int r = 0; r < 16; ++r) tm[r] = fmaxf(sA[r], sB[r]);
#pragma unroll
    for (int s = 8; s >= 1; s >>= 1)
#pragma unroll
      for (int r = 0; r < s; ++r) tm[r] = fmaxf(tm[r], tm[r + s]);
    const float pm = fmaxf(tm[0], __shfl_xor(tm[0], 32));

    if (!__all(pm <= m_r + 11.5416f)) {
      const float mnew = fmaxf(m_r, pm);
      const float corr = fexp2(m_r - mnew);
      l_r *= corr;
#pragma unroll
      for (int r = 0; r < 16; ++r) { oA[r] *= corr; oB[r] *= corr; }
      m_r = mnew;
    }

#pragma unroll
    for (int r = 0; r < 16; ++r) sA[r] = fexp2(sA[r] - m_r);
#pragma unroll
    for (int r = 0; r < 16; ++r) sB[r] = fexp2(sB[r] - m_r);

    float ts[16];
#pragma unroll
    for (int r = 0; r < 16; ++r) ts[r] = sA[r] + sB[r];
#pragma unroll
    for (int s = 8; s >= 1; s >>= 1)
#pragma unroll
      for (int r = 0; r < s; ++r) ts[r] += ts[r + s];
    l_r += ts[0];

    // ---- P^T fragments ----
    bf16x8 pf0 = pk_swap8(sA[0], sA[1], sA[2], sA[3], sA[4], sA[5], sA[6], sA[7]);
    bf16x8 pf1 = pk_swap8(sA[8], sA[9], sA[10], sA[11], sA[12], sA[13], sA[14], sA[15]);
    bf16x8 pf2 = pk_swap8(sB[0], sB[1], sB[2], sB[3], sB[4], sB[5], sB[6], sB[7]);
    bf16x8 pf3 = pk_swap8(sB[8], sB[9], sB[10], sB[11], sB[12], sB[13], sB[14], sB[15]);

    // ---- O^T += mfma(V^T, P^T) ----
    __builtin_amdgcn_s_setprio(1);
    oA = __builtin_amdgcn_mfma_f32_32x32x16_bf16(vA0, pf0, oA, 0, 0, 0);
    oB = __builtin_amdgcn_mfma_f32_32x32x16_bf16(vB0, pf0, oB, 0, 0, 0);
    oA = __builtin_amdgcn_mfma_f32_32x32x16_bf16(vA1, pf1, oA, 0, 0, 0);
    oB = __builtin_amdgcn_mfma_f32_32x32x16_bf16(vB1, pf1, oB, 0, 0, 0);
    oA = __builtin_amdgcn_mfma_f32_32x32x16_bf16(vA2, pf2, oA, 0, 0, 0);
    oB = __builtin_amdgcn_mfma_f32_32x32x16_bf16(vB2, pf2, oB, 0, 0, 0);
    oA = __builtin_amdgcn_mfma_f32_32x32x16_bf16(vA3, pf3, oA, 0, 0, 0);
    oB = __builtin_amdgcn_mfma_f32_32x32x16_bf16(vB3, pf3, oB, 0, 0, 0);
    __builtin_amdgcn_s_setprio(0);
  }

  // ---- epilogue ----
  const float lt = l_r + __shfl_xor(l_r, 32);
  const float inv = lt > 0.f ? 1.f / lt : 0.f;
#pragma unroll
  for (int r = 0; r < 16; ++r) { oA[r] *= inv; oB[r] *= inv; }

  bf16x8 e0 = pk_swap8(oA[0], oA[1], oA[2], oA[3], oA[4], oA[5], oA[6], oA[7]);
  bf16x8 e1 = pk_swap8(oA[8], oA[9], oA[10], oA[11], oA[12], oA[13], oA[14], oA[15]);
  bf16x8 e2 = pk_swap8(oB[0], oB[1], oB[2], oB[3], oB[4], oB[5], oB[6], oB[7]);
  bf16x8 e3 = pk_swap8(oB[8], oB[9], oB[10], oB[11], oB[12], oB[13], oB[14], oB[15]);

  if (lslot < 0) {
    bf16* ob = &out[(size_t)qrow * EMBED + h * HDIM];
    *(bf16x8*)(ob + hi * 8) = e0;
    *(bf16x8*)(ob + 16 + hi * 8) = e1;
    *(bf16x8*)(ob + 32 + hi * 8) = e2;
    *(bf16x8*)(ob + 48 + hi * 8) = e3;
  } else {
    const int gslot = h * 72 + lslot;
    bf16* base = (gslot < 1024)
                     ? (bf16*)((char*)partO_main + (size_t)gslot * 16384)
                     : (bf16*)((char*)partO_ovf + (size_t)(gslot - 1024) * 16384);
    const int lr = w * 32 + qi;
    bf16* pb = base + (size_t)lr * 64;
    *(bf16x8*)(pb + hi * 8) = e0;
    *(bf16x8*)(pb + 16 + hi * 8) = e1;
    *(bf16x8*)(pb + 32 + hi * 8) = e2;
    *(bf16x8*)(pb + 48 + hi * 8) = e3;
    if (hi == 0) partML[gslot * 128 + lr] = make_float2(m_r, lt);
  }
}

// ---------------------------------------------------------------------------
// Merge 2-4 kv-split partials (exp2 domain). Grid (24, HEADS), 256 thr.
// ---------------------------------------------------------------------------
__global__ __launch_bounds__(256) void merge_partials(
    const bf16* __restrict__ partO_main, const bf16* __restrict__ partO_ovf,
    const float2* __restrict__ partML, bf16* __restrict__ out) {
  const int qtb = 8 + blockIdx.x;
  const int h = blockIdx.y;
  int np, lbase;
  if (qtb < 16)      { np = 2; lbase = (qtb - 8) * 2; }
  else if (qtb < 24) { np = 3; lbase = 16 + (qtb - 16) * 3; }
  else               { np = 4; lbase = 40 + (qtb - 24) * 4; }
  const int gbase = h * 72 + lbase;
  const int r = threadIdx.x >> 1;
  const int dh = (threadIdx.x & 1) * 32;

  float mm = -INFINITY;
  float mv[4], lv[4];
#pragma unroll
  for (int p = 0; p < 4; ++p)
    if (p < np) {
      const float2 ml = partML[(gbase + p) * 128 + r];
      mv[p] = ml.x; lv[p] = ml.y;
      mm = fmaxf(mm, ml.x);
    }
  float wsum = 0.f, wgt[4];
#pragma unroll
  for (int p = 0; p < 4; ++p)
    if (p < np) {
      wgt[p] = lv[p] * fexp2(mv[p] - mm);
      wsum += wgt[p];
    }
  const float inv = 1.f / wsum;
#pragma unroll
  for (int p = 0; p < 4; ++p)
    if (p < np) wgt[p] *= inv;

  const bf16* pp[4];
#pragma unroll
  for (int p = 0; p < 4; ++p)
    if (p < np) {
      const int gs = gbase + p;
      const bf16* base = (gs < 1024)
                             ? (const bf16*)((const char*)partO_main + (size_t)gs * 16384)
                             : (const bf16*)((const char*)partO_ovf + (size_t)(gs - 1024) * 16384);
      pp[p] = base + (size_t)r * 64 + dh;
    }

  bf16* ob = &out[(size_t)(qtb * 128 + r) * EMBED + h * HDIM + dh];
#pragma unroll
  for (int c = 0; c < 4; ++c) {
    float acc[8] = {0.f, 0.f, 0.f, 0.f, 0.f, 0.f, 0.f, 0.f};
#pragma unroll
    for (int p = 0; p < 4; ++p)
      if (p < np) {
        bf16x8 v = *(const bf16x8*)(pp[p] + c * 8);
#pragma unroll
        for (int j = 0; j < 8; ++j) acc[j] += wgt[p] * (float)v[j];
      }
    bf16x8 o;
#pragma unroll
    for (int j = 0; j < 8; ++j) o[j] = (bf16)acc[j];
    *(bf16x8*)(ob + c * 8) = o;
  }
}

// ---------------------------------------------------------------------------
extern "C" void kernel_launch(void* const* d_in, const int* in_sizes, int n_in,
                              void* d_out, int out_size, void* d_ws, size_t ws_size,
                              hipStream_t stream) {
  const float* x     = (const float*)d_in[0];
  const float* W_qkv = (const float*)d_in[1];
  const float* b_qkv = (const float*)d_in[2];
  const float* W_out = (const float*)d_in[3];
  const float* b_out = (const float*)d_in[4];
  float* out = (float*)d_out;

  char* ws = (char*)d_ws;
  const size_t MB = 1024 * 1024;
  bf16* x_bf   = (bf16*)(ws + 0);        // 8 MB; dead after QKV gemm
  bf16* WqkvT  = (bf16*)(ws + 8 * MB);   // 6 MB; dead after QKV gemm
  bf16* WoutT  = (bf16*)(ws + 14 * MB);  // 2 MB (live to end)
  bf16* qkvb   = (bf16*)(ws + 16 * MB);  // 24 MB
  bf16* vT     = (bf16*)(ws + 40 * MB);  // 8 MB
  bf16* attn_o = (bf16*)(ws + 48 * MB);  // 8 MB
  // kv-split partials: slots 0..1023 in d_out (rewritten by final GEMM),
  // slots 1024..1151 over dead x_bf.
  bf16*   partO_main = (bf16*)d_out;
  bf16*   partO_ovf  = (bf16*)(ws + 0);
  float2* partML     = (float2*)(ws + 8 * MB);

  f32_to_bf16<<<(T_SEQ * EMBED) / (256 * 8), 256, 0, stream>>>(x, x_bf, T_SEQ * EMBED);
  transpose_f32_bf16<<<dim3(3 * EMBED / 32, EMBED / 32), 256, 0, stream>>>(
      W_qkv, WqkvT, EMBED, 3 * EMBED);
  transpose_f32_bf16<<<dim3(EMBED / 32, EMBED / 32), 256, 0, stream>>>(
      W_out, WoutT, EMBED, EMBED);

  gemm_bt_bias<false><<<dim3(3 * EMBED / 128, T_SEQ / 128), 256, 0, stream>>>(
      x_bf, WqkvT, b_qkv, qkvb, T_SEQ, 3 * EMBED, EMBED);

  transpose_v<<<dim3(T_SEQ / 64, HEADS), 256, 0, stream>>>(qkvb, vT);

  flash_attn_mfma<<<dim3(80, HEADS), 256, 0, stream>>>(qkvb, vT, attn_o, partO_main,
                                                       partO_ovf, partML);
  merge_partials<<<dim3(24, HEADS), 256, 0, stream>>>(partO_main, partO_ovf, partML,
                                                      attn_o);

  gemm_bt_bias<true><<<dim3(EMBED / 128, T_SEQ / 128), 256, 0, stream>>>(
      attn_o, WoutT, b_out, out, T_SEQ, EMBED, EMBED);
}

// Round 9
// 167.158 us; speedup vs baseline: 1.3801x; 1.3801x over previous
//
#include <hip/hip_runtime.h>
#include <hip/hip_bf16.h>
#include <math.h>

#define EMBED 1024
#define HEADS 16
#define HDIM 64
#define T_SEQ 4096

typedef __bf16 bf16;
typedef bf16 bf16x8 __attribute__((ext_vector_type(8)));
typedef float f32x4 __attribute__((ext_vector_type(4)));
typedef float f32x16 __attribute__((ext_vector_type(16)));

// async global->LDS, 16B per lane; LDS dest = wave-uniform base + lane*16.
#define GL(gp, lp)                                                            \
  __builtin_amdgcn_global_load_lds(                                           \
      (const __attribute__((address_space(1))) void*)(gp),                    \
      (__attribute__((address_space(3))) void*)(lp), 16, 0, 0)

// hardware 2^x
__device__ __forceinline__ float fexp2(float x) {
  float r;
  asm("v_exp_f32 %0, %1" : "=v"(r) : "v"(x));
  return r;
}

// ---------------------------------------------------------------------------
// fp32 -> bf16 elementwise (n % 8 == 0)
// ---------------------------------------------------------------------------
__global__ __launch_bounds__(256) void f32_to_bf16(
    const float* __restrict__ in, bf16* __restrict__ out, int n) {
  int i = (blockIdx.x * 256 + threadIdx.x) * 8;
  if (i >= n) return;
  float4 a = *(const float4*)&in[i];
  float4 b = *(const float4*)&in[i + 4];
  bf16x8 o;
  o[0] = (bf16)a.x; o[1] = (bf16)a.y; o[2] = (bf16)a.z; o[3] = (bf16)a.w;
  o[4] = (bf16)b.x; o[5] = (bf16)b.y; o[6] = (bf16)b.z; o[7] = (bf16)b.w;
  *(bf16x8*)&out[i] = o;
}

// ---------------------------------------------------------------------------
// Transpose fp32 [rows][cols] -> bf16 [cols][rows].
// ---------------------------------------------------------------------------
__global__ __launch_bounds__(256) void transpose_f32_bf16(
    const float* __restrict__ in, bf16* __restrict__ out, int rows, int cols) {
  __shared__ bf16 t[32][33];
  const int c0 = blockIdx.x * 32, r0 = blockIdx.y * 32;
  const int tx = threadIdx.x & 31, ty = threadIdx.x >> 5;
#pragma unroll
  for (int i = 0; i < 4; ++i)
    t[ty + 8 * i][tx] = (bf16)in[(size_t)(r0 + ty + 8 * i) * cols + c0 + tx];
  __syncthreads();
#pragma unroll
  for (int i = 0; i < 4; ++i)
    out[(size_t)(c0 + ty + 8 * i) * rows + r0 + tx] = t[tx][ty + 8 * i];
}

// ---------------------------------------------------------------------------
// Transpose V part of qkv into vT [H*64][T].
// ---------------------------------------------------------------------------
__global__ __launch_bounds__(256) void transpose_v(
    const bf16* __restrict__ qkvb, bf16* __restrict__ vT) {
  __shared__ bf16 t[64][65];
  const int h = blockIdx.y;
  const int t0 = blockIdx.x * 64;
  const int tx = threadIdx.x & 63, ty = threadIdx.x >> 6;
#pragma unroll
  for (int i = 0; i < 16; ++i)
    t[ty + 4 * i][tx] =
        qkvb[(size_t)(t0 + ty + 4 * i) * (3 * EMBED) + 2 * EMBED + h * HDIM + tx];
  __syncthreads();
#pragma unroll
  for (int i = 0; i < 16; ++i)
    vT[((size_t)h * HDIM + ty + 4 * i) * T_SEQ + t0 + tx] = t[tx][ty + 4 * i];
}

// ---------------------------------------------------------------------------
// bf16 MFMA GEMM:  C[M][N] = A[M][K] @ BT[N][K]^T + bias[N]
// 128x128 tile, BK=32, 4 waves. global_load_lds staging, double-buffered,
// raw s_barrier + counted vmcnt (prefetch never drained in main loop).
// ---------------------------------------------------------------------------
template <bool OUT_F32>
__global__ __launch_bounds__(256) void gemm_bt_bias(
    const bf16* __restrict__ A, const bf16* __restrict__ BT,
    const float* __restrict__ bias, void* __restrict__ Cout,
    int M, int N, int K) {
  __shared__ __align__(16) bf16 As[2][128 * 32];
  __shared__ __align__(16) bf16 Bs[2][128 * 32];
  const int tid = threadIdx.x;
  const int lane = tid & 63;
  const int w = tid >> 6;
  const int wr = w >> 1, wc = w & 1;
  const int l16 = lane & 15, lq = lane >> 4;
  const int brow = blockIdx.y * 128;
  const int bcol = blockIdx.x * 128;

  const int strow = w * 32 + (lane >> 2);
  const int stsl = (lane & 3) * 8;
  const bf16* Abase = A + (size_t)(brow + strow) * K + stsl;
  const bf16* Bbase = BT + (size_t)(bcol + strow) * K + stsl;

#define STAGE_G(buf, k0)                                        \
  {                                                             \
    GL(Abase + (k0), &As[buf][(w * 32) * 32]);                  \
    GL(Abase + (k0) + 16 * K, &As[buf][(w * 32 + 16) * 32]);    \
    GL(Bbase + (k0), &Bs[buf][(w * 32) * 32]);                  \
    GL(Bbase + (k0) + 16 * K, &Bs[buf][(w * 32 + 16) * 32]);    \
  }

  f32x4 acc[4][4] = {};
  const int NIT = K / 32;

  STAGE_G(0, 0);
  for (int it = 0; it < NIT; ++it) {
    const int cur = it & 1;
    if (it + 1 < NIT) {
      STAGE_G(cur ^ 1, (it + 1) * 32);
      asm volatile("s_waitcnt vmcnt(4)" ::: "memory");
    } else {
      asm volatile("s_waitcnt vmcnt(0)" ::: "memory");
    }
    __builtin_amdgcn_s_barrier();

    bf16x8 af[4], bfr[4];
#pragma unroll
    for (int m = 0; m < 4; ++m)
      af[m] = *(const bf16x8*)&As[cur][(wr * 64 + m * 16 + l16) * 32 + lq * 8];
#pragma unroll
    for (int n = 0; n < 4; ++n)
      bfr[n] = *(const bf16x8*)&Bs[cur][(wc * 64 + n * 16 + l16) * 32 + lq * 8];
#pragma unroll
    for (int m = 0; m < 4; ++m)
#pragma unroll
      for (int n = 0; n < 4; ++n)
        acc[m][n] =
            __builtin_amdgcn_mfma_f32_16x16x32_bf16(af[m], bfr[n], acc[m][n], 0, 0, 0);

    __builtin_amdgcn_s_barrier();
  }
#undef STAGE_G

#pragma unroll
  for (int m = 0; m < 4; ++m) {
    const int row = brow + wr * 64 + m * 16 + lq * 4;
#pragma unroll
    for (int n = 0; n < 4; ++n) {
      const int col = bcol + wc * 64 + n * 16 + l16;
      const float bv = bias[col];
#pragma unroll
      for (int r2 = 0; r2 < 4; ++r2) {
        float v = acc[m][n][r2] + bv;
        if (OUT_F32)
          ((float*)Cout)[(size_t)(row + r2) * N + col] = v;
        else
          ((bf16*)Cout)[(size_t)(row + r2) * N + col] = (bf16)v;
      }
    }
  }
}

// ---------------------------------------------------------------------------
// cvt_pk + permlane32_swap packing helper.
// ---------------------------------------------------------------------------
__device__ __forceinline__ bf16x8 pk_swap8(float a0, float a1, float a2, float a3,
                                           float a4, float a5, float a6, float a7) {
  unsigned W0, W1, W2, W3;
  asm("v_cvt_pk_bf16_f32 %0, %1, %2" : "=v"(W0) : "v"(a0), "v"(a1));
  asm("v_cvt_pk_bf16_f32 %0, %1, %2" : "=v"(W1) : "v"(a2), "v"(a3));
  asm("v_cvt_pk_bf16_f32 %0, %1, %2" : "=v"(W2) : "v"(a4), "v"(a5));
  asm("v_cvt_pk_bf16_f32 %0, %1, %2" : "=v"(W3) : "v"(a6), "v"(a7));
  asm("v_permlane32_swap_b32 %0, %1" : "+v"(W0), "+v"(W2));
  asm("v_permlane32_swap_b32 %0, %1" : "+v"(W1), "+v"(W3));
  union { unsigned u[4]; bf16x8 v; } r;
  r.u[0] = W0; r.u[1] = W1; r.u[2] = W2; r.u[3] = W3;
  return r.v;
}

// ---------------------------------------------------------------------------
// Flash attention, swapped layout, exp2 domain, KV-split cap 12 tiles/job.
// Per head 102 jobs: qtb 0..5 direct; qtb>=6 split into ceil((2qtb+2)/12)
// parts. gload_lds double-buffered staging (linear dest + pre-swizzled
// source), raw s_barrier + counted vmcnt(4) (drain only on last tile).
// Partial slots (96/head): 0..1023 in d_out, 1024..1535 over dead x_bf.
// ---------------------------------------------------------------------------
__global__ __launch_bounds__(256) void flash_attn_mfma(
    const bf16* __restrict__ qkvb, const bf16* __restrict__ vT,
    bf16* __restrict__ out, bf16* __restrict__ partO_main,
    bf16* __restrict__ partO_ovf, float2* __restrict__ partML) {
  const int h = blockIdx.y;
  const int job = 101 - (int)blockIdx.x;  // big jobs first
  int qtb, np, part;
  if (job < 6)       { qtb = job;                      np = 1; part = 0; }
  else if (job < 18) { int t = job - 6;  qtb = 6 + (t >> 1);  np = 2; part = t & 1; }
  else if (job < 36) { int t = job - 18; qtb = 12 + t / 3;    np = 3; part = t - (t / 3) * 3; }
  else if (job < 60) { int t = job - 36; qtb = 18 + (t >> 2); np = 4; part = t & 3; }
  else if (job < 90) { int t = job - 60; qtb = 24 + t / 5;    np = 5; part = t - (t / 5) * 5; }
  else               { int t = job - 90; qtb = 30 + t / 6;    np = 6; part = t - (t / 6) * 6; }
  const int nt = 2 * qtb + 2;
  const int bsz = nt / np, rem = nt % np;
  const int k0t = part * bsz + min(part, rem);
  const int k1t = k0t + bsz + (part < rem ? 1 : 0);

  int lslot = -1;
  if (np > 1) {
    if (qtb < 12)      lslot = (qtb - 6) * 2 + part;
    else if (qtb < 18) lslot = 12 + (qtb - 12) * 3 + part;
    else if (qtb < 24) lslot = 30 + (qtb - 18) * 4 + part;
    else if (qtb < 30) lslot = 54 + (qtb - 24) * 5 + part;
    else               lslot = 84 + (qtb - 30) * 6 + part;
  }

  const int q0 = qtb * 128;
  const int tid = threadIdx.x;
  const int lane = tid & 63;
  const int w = tid >> 6;
  const int qi = lane & 31;   // q index within wave tile
  const int hi = lane >> 5;   // k-half selector

  __shared__ __align__(16) bf16 Ks[2][64 * 64];  // [key][d], swizzled content
  __shared__ __align__(16) bf16 Vs[2][64 * 64];  // [d][key], swizzled content

  const int qrow = q0 + w * 32 + qi;

  // Q B-fragments, pre-scaled by 0.125*log2(e) (exp2-domain softmax)
  const float QSCALE = 0.1803368867f;
  bf16x8 qb0, qb1, qb2, qb3;
  {
    const bf16* qp = &qkvb[(size_t)qrow * (3 * EMBED) + h * HDIM + hi * 8];
    qb0 = *(const bf16x8*)(qp + 0);
    qb1 = *(const bf16x8*)(qp + 16);
    qb2 = *(const bf16x8*)(qp + 32);
    qb3 = *(const bf16x8*)(qp + 48);
#pragma unroll
    for (int j = 0; j < 8; ++j) {
      qb0[j] = (bf16)((float)qb0[j] * QSCALE);
      qb1[j] = (bf16)((float)qb1[j] * QSCALE);
      qb2[j] = (bf16)((float)qb2[j] * QSCALE);
      qb3[j] = (bf16)((float)qb3[j] * QSCALE);
    }
  }

  f32x16 oA = {}, oB = {};
  float m_r = -INFINITY, l_r = 0.f;

  // staging: wave w stages rows [w*16, w*16+16) of each 64-row tile in two
  // 8-row GLs. lane l: row = chunk + (l>>3), dest 16B-slot l&7; source slot
  // pre-swizzled (l&7)^(row&7) so LDS content is swizzled, reads unchanged.
  const int krow = lane >> 3;                  // 0..7
  const int ksl = ((lane & 7) ^ krow) * 8;     // source elem offset in row
  const bf16* Kbase =
      qkvb + (size_t)(w * 16 + krow) * (3 * EMBED) + EMBED + h * HDIM + ksl;
  const bf16* Vbase = vT + ((size_t)h * HDIM + w * 16 + krow) * T_SEQ + ksl;

#define STAGE_KV(buf, kt)                                                      \
  {                                                                            \
    GL(Kbase + (size_t)(kt) * 64 * (3 * EMBED), &Ks[buf][(w * 16) * 64]);      \
    GL(Kbase + (size_t)(kt) * 64 * (3 * EMBED) + (size_t)8 * (3 * EMBED),      \
       &Ks[buf][(w * 16 + 8) * 64]);                                           \
    GL(Vbase + (kt) * 64, &Vs[buf][(w * 16) * 64]);                            \
    GL(Vbase + (kt) * 64 + 8 * T_SEQ, &Vs[buf][(w * 16 + 8) * 64]);            \
  }

  STAGE_KV(0, k0t);
  for (int kt = k0t; kt < k1t; ++kt) {
    const int cur = (kt - k0t) & 1;
    if (kt + 1 < k1t) {
      STAGE_KV(cur ^ 1, kt + 1);                        // prefetch 4 loads
      asm volatile("s_waitcnt vmcnt(4)" ::: "memory");  // wait only cur's 4
    } else {
      asm volatile("s_waitcnt vmcnt(0)" ::: "memory");  // last tile: drain
    }
    __builtin_amdgcn_s_barrier();  // all waves' cur loads landed

    if (!(kt * 64 > q0 + w * 32 + 31)) {
      // ---- S^T = mfma(K, Q) ----
      f32x16 sA = {}, sB = {};
      __builtin_amdgcn_s_setprio(1);
#pragma unroll
      for (int c = 0; c < 4; ++c) {
        const int sl = ((2 * c + hi) ^ (qi & 7)) << 3;
        bf16x8 kfA = *(const bf16x8*)&Ks[cur][qi * 64 + sl];
        bf16x8 kfB = *(const bf16x8*)&Ks[cur][(qi + 32) * 64 + sl];
        bf16x8 qf = (c == 0) ? qb0 : (c == 1) ? qb1 : (c == 2) ? qb2 : qb3;
        sA = __builtin_amdgcn_mfma_f32_32x32x16_bf16(kfA, qf, sA, 0, 0, 0);
        sB = __builtin_amdgcn_mfma_f32_32x32x16_bf16(kfB, qf, sB, 0, 0, 0);
      }
      __builtin_amdgcn_s_setprio(0);

      // ---- causal mask (only near the diagonal) ----
      if (kt * 64 + 63 > q0 + w * 32) {
        const int qg = qrow;
#pragma unroll
        for (int r = 0; r < 16; ++r) {
          const int kl = (r & 3) + 8 * (r >> 2) + 4 * hi;
          if (kt * 64 + kl > qg) sA[r] = -INFINITY;
          if (kt * 64 + 32 + kl > qg) sB[r] = -INFINITY;
        }
      }

      // ---- online softmax (exp2 domain) ----
      float tm[16];
#pragma unroll
      for (int r = 0; r < 16; ++r) tm[r] = fmaxf(sA[r], sB[r]);
#pragma unroll
      for (int s = 8; s >= 1; s >>= 1)
#pragma unroll
        for (int r = 0; r < s; ++r) tm[r] = fmaxf(tm[r], tm[r + s]);
      const float pm = fmaxf(tm[0], __shfl_xor(tm[0], 32));

      if (!__all(pm <= m_r + 11.5416f)) {
        const float mnew = fmaxf(m_r, pm);
        const float corr = fexp2(m_r - mnew);
        l_r *= corr;
#pragma unroll
        for (int r = 0; r < 16; ++r) { oA[r] *= corr; oB[r] *= corr; }
        m_r = mnew;
      }

#pragma unroll
      for (int r = 0; r < 16; ++r) sA[r] = fexp2(sA[r] - m_r);
#pragma unroll
      for (int r = 0; r < 16; ++r) sB[r] = fexp2(sB[r] - m_r);

      float ts[16];
#pragma unroll
      for (int r = 0; r < 16; ++r) ts[r] = sA[r] + sB[r];
#pragma unroll
      for (int s = 8; s >= 1; s >>= 1)
#pragma unroll
        for (int r = 0; r < s; ++r) ts[r] += ts[r + s];
      l_r += ts[0];

      // ---- P^T fragments ----
      bf16x8 pf0 = pk_swap8(sA[0], sA[1], sA[2], sA[3], sA[4], sA[5], sA[6], sA[7]);
      bf16x8 pf1 = pk_swap8(sA[8], sA[9], sA[10], sA[11], sA[12], sA[13], sA[14], sA[15]);
      bf16x8 pf2 = pk_swap8(sB[0], sB[1], sB[2], sB[3], sB[4], sB[5], sB[6], sB[7]);
      bf16x8 pf3 = pk_swap8(sB[8], sB[9], sB[10], sB[11], sB[12], sB[13], sB[14], sB[15]);

      // ---- O^T += mfma(V^T, P^T) ----
      __builtin_amdgcn_s_setprio(1);
#pragma unroll
      for (int c = 0; c < 4; ++c) {
        const int sl = ((2 * c + hi) ^ (qi & 7)) << 3;
        bf16x8 vfA = *(const bf16x8*)&Vs[cur][qi * 64 + sl];
        bf16x8 vfB = *(const bf16x8*)&Vs[cur][(qi + 32) * 64 + sl];
        bf16x8 pf = (c == 0) ? pf0 : (c == 1) ? pf1 : (c == 2) ? pf2 : pf3;
        oA = __builtin_amdgcn_mfma_f32_32x32x16_bf16(vfA, pf, oA, 0, 0, 0);
        oB = __builtin_amdgcn_mfma_f32_32x32x16_bf16(vfB, pf, oB, 0, 0, 0);
      }
      __builtin_amdgcn_s_setprio(0);
    }

    __builtin_amdgcn_s_barrier();  // buf cur reads done; next stage may overwrite
  }
#undef STAGE_KV

  // ---- epilogue ----
  const float lt = l_r + __shfl_xor(l_r, 32);
  const float inv = lt > 0.f ? 1.f / lt : 0.f;
#pragma unroll
  for (int r = 0; r < 16; ++r) { oA[r] *= inv; oB[r] *= inv; }

  bf16x8 e0 = pk_swap8(oA[0], oA[1], oA[2], oA[3], oA[4], oA[5], oA[6], oA[7]);
  bf16x8 e1 = pk_swap8(oA[8], oA[9], oA[10], oA[11], oA[12], oA[13], oA[14], oA[15]);
  bf16x8 e2 = pk_swap8(oB[0], oB[1], oB[2], oB[3], oB[4], oB[5], oB[6], oB[7]);
  bf16x8 e3 = pk_swap8(oB[8], oB[9], oB[10], oB[11], oB[12], oB[13], oB[14], oB[15]);

  if (lslot < 0) {
    bf16* ob = &out[(size_t)qrow * EMBED + h * HDIM];
    *(bf16x8*)(ob + hi * 8) = e0;
    *(bf16x8*)(ob + 16 + hi * 8) = e1;
    *(bf16x8*)(ob + 32 + hi * 8) = e2;
    *(bf16x8*)(ob + 48 + hi * 8) = e3;
  } else {
    const int gslot = h * 96 + lslot;
    bf16* base = (gslot < 1024)
                     ? (bf16*)((char*)partO_main + (size_t)gslot * 16384)
                     : (bf16*)((char*)partO_ovf + (size_t)(gslot - 1024) * 16384);
    const int lr = w * 32 + qi;
    bf16* pb = base + (size_t)lr * 64;
    *(bf16x8*)(pb + hi * 8) = e0;
    *(bf16x8*)(pb + 16 + hi * 8) = e1;
    *(bf16x8*)(pb + 32 + hi * 8) = e2;
    *(bf16x8*)(pb + 48 + hi * 8) = e3;
    if (hi == 0) partML[gslot * 128 + lr] = make_float2(m_r, lt);
  }
}

// ---------------------------------------------------------------------------
// Merge 2-6 kv-split partials (exp2 domain). Grid (26, HEADS), 256 thr.
// ---------------------------------------------------------------------------
__global__ __launch_bounds__(256) void merge_partials(
    const bf16* __restrict__ partO_main, const bf16* __restrict__ partO_ovf,
    const float2* __restrict__ partML, bf16* __restrict__ out) {
  const int qtb = 6 + blockIdx.x;
  const int h = blockIdx.y;
  int np, lbase;
  if (qtb < 12)      { np = 2; lbase = (qtb - 6) * 2; }
  else if (qtb < 18) { np = 3; lbase = 12 + (qtb - 12) * 3; }
  else if (qtb < 24) { np = 4; lbase = 30 + (qtb - 18) * 4; }
  else if (qtb < 30) { np = 5; lbase = 54 + (qtb - 24) * 5; }
  else               { np = 6; lbase = 84 + (qtb - 30) * 6; }
  const int gbase = h * 96 + lbase;
  const int r = threadIdx.x >> 1;
  const int dh = (threadIdx.x & 1) * 32;

  float mm = -INFINITY;
  float mv[6], lv[6];
#pragma unroll
  for (int p = 0; p < 6; ++p)
    if (p < np) {
      const float2 ml = partML[(gbase + p) * 128 + r];
      mv[p] = ml.x; lv[p] = ml.y;
      mm = fmaxf(mm, ml.x);
    }
  float wsum = 0.f, wgt[6];
#pragma unroll
  for (int p = 0; p < 6; ++p)
    if (p < np) {
      wgt[p] = lv[p] * fexp2(mv[p] - mm);
      wsum += wgt[p];
    }
  const float inv = 1.f / wsum;
#pragma unroll
  for (int p = 0; p < 6; ++p)
    if (p < np) wgt[p] *= inv;

  const bf16* pp[6];
#pragma unroll
  for (int p = 0; p < 6; ++p)
    if (p < np) {
      const int gs = gbase + p;
      const bf16* base = (gs < 1024)
                             ? (const bf16*)((const char*)partO_main + (size_t)gs * 16384)
                             : (const bf16*)((const char*)partO_ovf + (size_t)(gs - 1024) * 16384);
      pp[p] = base + (size_t)r * 64 + dh;
    }

  bf16* ob = &out[(size_t)(qtb * 128 + r) * EMBED + h * HDIM + dh];
#pragma unroll
  for (int c = 0; c < 4; ++c) {
    float acc[8] = {0.f, 0.f, 0.f, 0.f, 0.f, 0.f, 0.f, 0.f};
#pragma unroll
    for (int p = 0; p < 6; ++p)
      if (p < np) {
        bf16x8 v = *(const bf16x8*)(pp[p] + c * 8);
#pragma unroll
        for (int j = 0; j < 8; ++j) acc[j] += wgt[p] * (float)v[j];
      }
    bf16x8 o;
#pragma unroll
    for (int j = 0; j < 8; ++j) o[j] = (bf16)acc[j];
    *(bf16x8*)(ob + c * 8) = o;
  }
}

// ---------------------------------------------------------------------------
extern "C" void kernel_launch(void* const* d_in, const int* in_sizes, int n_in,
                              void* d_out, int out_size, void* d_ws, size_t ws_size,
                              hipStream_t stream) {
  const float* x     = (const float*)d_in[0];
  const float* W_qkv = (const float*)d_in[1];
  const float* b_qkv = (const float*)d_in[2];
  const float* W_out = (const float*)d_in[3];
  const float* b_out = (const float*)d_in[4];
  float* out = (float*)d_out;

  char* ws = (char*)d_ws;
  const size_t MB = 1024 * 1024;
  bf16* x_bf   = (bf16*)(ws + 0);        // 8 MB; dead after QKV gemm
  bf16* WqkvT  = (bf16*)(ws + 8 * MB);   // 6 MB; dead after QKV gemm
  bf16* WoutT  = (bf16*)(ws + 14 * MB);  // 2 MB (live to end)
  bf16* qkvb   = (bf16*)(ws + 16 * MB);  // 24 MB
  bf16* vT     = (bf16*)(ws + 40 * MB);  // 8 MB
  bf16* attn_o = (bf16*)(ws + 48 * MB);  // 8 MB
  // kv-split partials: 1536 slots x 16 KB. 0..1023 in d_out (rewritten by
  // final GEMM), 1024..1535 over dead x_bf (exactly 8 MB). partML over WqkvT.
  bf16*   partO_main = (bf16*)d_out;
  bf16*   partO_ovf  = (bf16*)(ws + 0);
  float2* partML     = (float2*)(ws + 8 * MB);  // 1536*128*8B = 1.5 MB

  f32_to_bf16<<<(T_SEQ * EMBED) / (256 * 8), 256, 0, stream>>>(x, x_bf, T_SEQ * EMBED);
  transpose_f32_bf16<<<dim3(3 * EMBED / 32, EMBED / 32), 256, 0, stream>>>(
      W_qkv, WqkvT, EMBED, 3 * EMBED);
  transpose_f32_bf16<<<dim3(EMBED / 32, EMBED / 32), 256, 0, stream>>>(
      W_out, WoutT, EMBED, EMBED);

  gemm_bt_bias<false><<<dim3(3 * EMBED / 128, T_SEQ / 128), 256, 0, stream>>>(
      x_bf, WqkvT, b_qkv, qkvb, T_SEQ, 3 * EMBED, EMBED);

  transpose_v<<<dim3(T_SEQ / 64, HEADS), 256, 0, stream>>>(qkvb, vT);

  flash_attn_mfma<<<dim3(102, HEADS), 256, 0, stream>>>(qkvb, vT, attn_o, partO_main,
                                                        partO_ovf, partML);
  merge_partials<<<dim3(26, HEADS), 256, 0, stream>>>(partO_main, partO_ovf, partML,
                                                      attn_o);

  gemm_bt_bias<true><<<dim3(EMBED / 128, T_SEQ / 128), 256, 0, stream>>>(
      attn_o, WoutT, b_out, out, T_SEQ, EMBED, EMBED);
}

// Round 11
// 162.919 us; speedup vs baseline: 1.4160x; 1.0260x over previous
//
#include <hip/hip_runtime.h>
#include <hip/hip_bf16.h>
#include <math.h>

#define EMBED 1024
#define HEADS 16
#define HDIM 64
#define T_SEQ 4096

typedef __bf16 bf16;
typedef bf16 bf16x8 __attribute__((ext_vector_type(8)));
typedef float f32x4 __attribute__((ext_vector_type(4)));
typedef float f32x16 __attribute__((ext_vector_type(16)));

// async global->LDS, 16B per lane; LDS dest = wave-uniform base + lane*16.
#define GL(gp, lp)                                                            \
  __builtin_amdgcn_global_load_lds(                                           \
      (const __attribute__((address_space(1))) void*)(gp),                    \
      (__attribute__((address_space(3))) void*)(lp), 16, 0, 0)

// hardware 2^x
__device__ __forceinline__ float fexp2(float x) {
  float r;
  asm("v_exp_f32 %0, %1" : "=v"(r) : "v"(x));
  return r;
}

// ---------------------------------------------------------------------------
// fp32 -> bf16 elementwise (n % 8 == 0)
// ---------------------------------------------------------------------------
__global__ __launch_bounds__(256) void f32_to_bf16(
    const float* __restrict__ in, bf16* __restrict__ out, int n) {
  int i = (blockIdx.x * 256 + threadIdx.x) * 8;
  if (i >= n) return;
  float4 a = *(const float4*)&in[i];
  float4 b = *(const float4*)&in[i + 4];
  bf16x8 o;
  o[0] = (bf16)a.x; o[1] = (bf16)a.y; o[2] = (bf16)a.z; o[3] = (bf16)a.w;
  o[4] = (bf16)b.x; o[5] = (bf16)b.y; o[6] = (bf16)b.z; o[7] = (bf16)b.w;
  *(bf16x8*)&out[i] = o;
}

// ---------------------------------------------------------------------------
// Transpose fp32 [rows][cols] -> bf16 [cols][rows].
// ---------------------------------------------------------------------------
__global__ __launch_bounds__(256) void transpose_f32_bf16(
    const float* __restrict__ in, bf16* __restrict__ out, int rows, int cols) {
  __shared__ bf16 t[32][33];
  const int c0 = blockIdx.x * 32, r0 = blockIdx.y * 32;
  const int tx = threadIdx.x & 31, ty = threadIdx.x >> 5;
#pragma unroll
  for (int i = 0; i < 4; ++i)
    t[ty + 8 * i][tx] = (bf16)in[(size_t)(r0 + ty + 8 * i) * cols + c0 + tx];
  __syncthreads();
#pragma unroll
  for (int i = 0; i < 4; ++i)
    out[(size_t)(c0 + ty + 8 * i) * rows + r0 + tx] = t[tx][ty + 8 * i];
}

// ---------------------------------------------------------------------------
// Transpose V part of qkv into vT [H*64][T].
// ---------------------------------------------------------------------------
__global__ __launch_bounds__(256) void transpose_v(
    const bf16* __restrict__ qkvb, bf16* __restrict__ vT) {
  __shared__ bf16 t[64][65];
  const int h = blockIdx.y;
  const int t0 = blockIdx.x * 64;
  const int tx = threadIdx.x & 63, ty = threadIdx.x >> 6;
#pragma unroll
  for (int i = 0; i < 16; ++i)
    t[ty + 4 * i][tx] =
        qkvb[(size_t)(t0 + ty + 4 * i) * (3 * EMBED) + 2 * EMBED + h * HDIM + tx];
  __syncthreads();
#pragma unroll
  for (int i = 0; i < 16; ++i)
    vT[((size_t)h * HDIM + ty + 4 * i) * T_SEQ + t0 + tx] = t[tx][ty + 4 * i];
}

// ---------------------------------------------------------------------------
// bf16 MFMA GEMM:  C[M][N] = A[M][K] @ BT[N][K]^T + bias[N]
// 128x128 tile, BK=32, 4 waves. gload_lds dbuf, SINGLE barrier per K-step:
// {STAGE(next); compute(cur); vmcnt(0); s_barrier}.
// ---------------------------------------------------------------------------
template <bool OUT_F32>
__global__ __launch_bounds__(256) void gemm_bt_bias(
    const bf16* __restrict__ A, const bf16* __restrict__ BT,
    const float* __restrict__ bias, void* __restrict__ Cout,
    int M, int N, int K) {
  __shared__ __align__(16) bf16 As[2][128 * 32];
  __shared__ __align__(16) bf16 Bs[2][128 * 32];
  const int tid = threadIdx.x;
  const int lane = tid & 63;
  const int w = tid >> 6;
  const int wr = w >> 1, wc = w & 1;
  const int l16 = lane & 15, lq = lane >> 4;
  const int brow = blockIdx.y * 128;
  const int bcol = blockIdx.x * 128;

  const int strow = w * 32 + (lane >> 2);
  const int stsl = (lane & 3) * 8;
  const bf16* Abase = A + (size_t)(brow + strow) * K + stsl;
  const bf16* Bbase = BT + (size_t)(bcol + strow) * K + stsl;

#define STAGE_G(buf, k0)                                        \
  {                                                             \
    GL(Abase + (k0), &As[buf][(w * 32) * 32]);                  \
    GL(Abase + (k0) + 16 * K, &As[buf][(w * 32 + 16) * 32]);    \
    GL(Bbase + (k0), &Bs[buf][(w * 32) * 32]);                  \
    GL(Bbase + (k0) + 16 * K, &Bs[buf][(w * 32 + 16) * 32]);    \
  }

  f32x4 acc[4][4] = {};
  const int NIT = K / 32;

  STAGE_G(0, 0);
  asm volatile("s_waitcnt vmcnt(0)" ::: "memory");
  __builtin_amdgcn_s_barrier();

  for (int it = 0; it < NIT; ++it) {
    const int cur = it & 1;
    if (it + 1 < NIT) STAGE_G(cur ^ 1, (it + 1) * 32);  // async, hides under compute

    bf16x8 af[4], bfr[4];
#pragma unroll
    for (int m = 0; m < 4; ++m)
      af[m] = *(const bf16x8*)&As[cur][(wr * 64 + m * 16 + l16) * 32 + lq * 8];
#pragma unroll
    for (int n = 0; n < 4; ++n)
      bfr[n] = *(const bf16x8*)&Bs[cur][(wc * 64 + n * 16 + l16) * 32 + lq * 8];
#pragma unroll
    for (int m = 0; m < 4; ++m)
#pragma unroll
      for (int n = 0; n < 4; ++n)
        acc[m][n] =
            __builtin_amdgcn_mfma_f32_16x16x32_bf16(af[m], bfr[n], acc[m][n], 0, 0, 0);

    asm volatile("s_waitcnt vmcnt(0)" ::: "memory");  // next-tile loads landed
    __builtin_amdgcn_s_barrier();                     // + all waves' reads done
  }
#undef STAGE_G

#pragma unroll
  for (int m = 0; m < 4; ++m) {
    const int row = brow + wr * 64 + m * 16 + lq * 4;
#pragma unroll
    for (int n = 0; n < 4; ++n) {
      const int col = bcol + wc * 64 + n * 16 + l16;
      const float bv = bias[col];
#pragma unroll
      for (int r2 = 0; r2 < 4; ++r2) {
        float v = acc[m][n][r2] + bv;
        if (OUT_F32)
          ((float*)Cout)[(size_t)(row + r2) * N + col] = v;
        else
          ((bf16*)Cout)[(size_t)(row + r2) * N + col] = (bf16)v;
      }
    }
  }
}

// ---------------------------------------------------------------------------
// cvt_pk + permlane32_swap packing helper (distinct-value operands: safe).
// ---------------------------------------------------------------------------
__device__ __forceinline__ bf16x8 pk_swap8(float a0, float a1, float a2, float a3,
                                           float a4, float a5, float a6, float a7) {
  unsigned W0, W1, W2, W3;
  asm("v_cvt_pk_bf16_f32 %0, %1, %2" : "=v"(W0) : "v"(a0), "v"(a1));
  asm("v_cvt_pk_bf16_f32 %0, %1, %2" : "=v"(W1) : "v"(a2), "v"(a3));
  asm("v_cvt_pk_bf16_f32 %0, %1, %2" : "=v"(W2) : "v"(a4), "v"(a5));
  asm("v_cvt_pk_bf16_f32 %0, %1, %2" : "=v"(W3) : "v"(a6), "v"(a7));
  asm("v_permlane32_swap_b32 %0, %1" : "+v"(W0), "+v"(W2));
  asm("v_permlane32_swap_b32 %0, %1" : "+v"(W1), "+v"(W3));
  union { unsigned u[4]; bf16x8 v; } r;
  r.u[0] = W0; r.u[1] = W1; r.u[2] = W2; r.u[3] = W3;
  return r.v;
}

// ---------------------------------------------------------------------------
// Flash attention, swapped layout, exp2 domain, KV-split cap 12 tiles/job.
// 1-D XCD-aware grid (1632): h = bid & 15, job = 101 - (bid >> 4) — dispatch
// round-robins XCDs and 16%8==0, so each XCD serves exactly 2 heads -> 2 MB
// KV per XCD L2 (resident). Single barrier per tile. Cross-half reductions
// via __shfl_xor(…,32) (round-10 permlane reduction was miscompiled -> NaN).
// ---------------------------------------------------------------------------
__global__ __launch_bounds__(256) void flash_attn_mfma(
    const bf16* __restrict__ qkvb, const bf16* __restrict__ vT,
    bf16* __restrict__ out, bf16* __restrict__ partO_main,
    bf16* __restrict__ partO_ovf, float2* __restrict__ partML) {
  const int bid = (int)blockIdx.x;
  const int h = bid & 15;
  const int job = 101 - (bid >> 4);  // big jobs first per head
  int qtb, np, part;
  if (job < 6)       { qtb = job;                      np = 1; part = 0; }
  else if (job < 18) { int t = job - 6;  qtb = 6 + (t >> 1);  np = 2; part = t & 1; }
  else if (job < 36) { int t = job - 18; qtb = 12 + t / 3;    np = 3; part = t - (t / 3) * 3; }
  else if (job < 60) { int t = job - 36; qtb = 18 + (t >> 2); np = 4; part = t & 3; }
  else if (job < 90) { int t = job - 60; qtb = 24 + t / 5;    np = 5; part = t - (t / 5) * 5; }
  else               { int t = job - 90; qtb = 30 + t / 6;    np = 6; part = t - (t / 6) * 6; }
  const int nt = 2 * qtb + 2;
  const int bsz = nt / np, rem = nt % np;
  const int k0t = part * bsz + min(part, rem);
  const int k1t = k0t + bsz + (part < rem ? 1 : 0);

  int lslot = -1;
  if (np > 1) {
    if (qtb < 12)      lslot = (qtb - 6) * 2 + part;
    else if (qtb < 18) lslot = 12 + (qtb - 12) * 3 + part;
    else if (qtb < 24) lslot = 30 + (qtb - 18) * 4 + part;
    else if (qtb < 30) lslot = 54 + (qtb - 24) * 5 + part;
    else               lslot = 84 + (qtb - 30) * 6 + part;
  }

  const int q0 = qtb * 128;
  const int tid = threadIdx.x;
  const int lane = tid & 63;
  const int w = tid >> 6;
  const int qi = lane & 31;   // q index within wave tile
  const int hi = lane >> 5;   // k-half selector

  __shared__ __align__(16) bf16 Ks[2][64 * 64];  // [key][d], swizzled content
  __shared__ __align__(16) bf16 Vs[2][64 * 64];  // [d][key], swizzled content

  const int qrow = q0 + w * 32 + qi;

  // Q B-fragments, pre-scaled by 0.125*log2(e) (exp2-domain softmax)
  const float QSCALE = 0.1803368867f;
  bf16x8 qb0, qb1, qb2, qb3;
  {
    const bf16* qp = &qkvb[(size_t)qrow * (3 * EMBED) + h * HDIM + hi * 8];
    qb0 = *(const bf16x8*)(qp + 0);
    qb1 = *(const bf16x8*)(qp + 16);
    qb2 = *(const bf16x8*)(qp + 32);
    qb3 = *(const bf16x8*)(qp + 48);
#pragma unroll
    for (int j = 0; j < 8; ++j) {
      qb0[j] = (bf16)((float)qb0[j] * QSCALE);
      qb1[j] = (bf16)((float)qb1[j] * QSCALE);
      qb2[j] = (bf16)((float)qb2[j] * QSCALE);
      qb3[j] = (bf16)((float)qb3[j] * QSCALE);
    }
  }

  f32x16 oA = {}, oB = {};
  float m_r = -INFINITY, l_r = 0.f;

  // staging: wave w stages rows [w*16, w*16+16) in two 8-row GLs; lane l:
  // row = chunk + (l>>3), dest slot l&7, source slot (l&7)^(row&7).
  const int krow = lane >> 3;
  const int ksl = ((lane & 7) ^ krow) * 8;
  const bf16* Kbase =
      qkvb + (size_t)(w * 16 + krow) * (3 * EMBED) + EMBED + h * HDIM + ksl;
  const bf16* Vbase = vT + ((size_t)h * HDIM + w * 16 + krow) * T_SEQ + ksl;

#define STAGE_KV(buf, kt)                                                      \
  {                                                                            \
    GL(Kbase + (size_t)(kt) * 64 * (3 * EMBED), &Ks[buf][(w * 16) * 64]);      \
    GL(Kbase + (size_t)(kt) * 64 * (3 * EMBED) + (size_t)8 * (3 * EMBED),      \
       &Ks[buf][(w * 16 + 8) * 64]);                                           \
    GL(Vbase + (kt) * 64, &Vs[buf][(w * 16) * 64]);                            \
    GL(Vbase + (kt) * 64 + 8 * T_SEQ, &Vs[buf][(w * 16 + 8) * 64]);            \
  }

  STAGE_KV(0, k0t);
  asm volatile("s_waitcnt vmcnt(0)" ::: "memory");
  __builtin_amdgcn_s_barrier();

  for (int kt = k0t; kt < k1t; ++kt) {
    const int cur = (kt - k0t) & 1;
    if (kt + 1 < k1t) STAGE_KV(cur ^ 1, kt + 1);  // async; hides under compute

    if (!(kt * 64 > q0 + w * 32 + 31)) {
      // ---- S^T = mfma(K, Q) ----
      f32x16 sA = {}, sB = {};
      __builtin_amdgcn_s_setprio(1);
#pragma unroll
      for (int c = 0; c < 4; ++c) {
        const int sl = ((2 * c + hi) ^ (qi & 7)) << 3;
        bf16x8 kfA = *(const bf16x8*)&Ks[cur][qi * 64 + sl];
        bf16x8 kfB = *(const bf16x8*)&Ks[cur][(qi + 32) * 64 + sl];
        bf16x8 qf = (c == 0) ? qb0 : (c == 1) ? qb1 : (c == 2) ? qb2 : qb3;
        sA = __builtin_amdgcn_mfma_f32_32x32x16_bf16(kfA, qf, sA, 0, 0, 0);
        sB = __builtin_amdgcn_mfma_f32_32x32x16_bf16(kfB, qf, sB, 0, 0, 0);
      }
      __builtin_amdgcn_s_setprio(0);

      // ---- causal mask (only near the diagonal) ----
      if (kt * 64 + 63 > q0 + w * 32) {
        const int qg = qrow;
#pragma unroll
        for (int r = 0; r < 16; ++r) {
          const int kl = (r & 3) + 8 * (r >> 2) + 4 * hi;
          if (kt * 64 + kl > qg) sA[r] = -INFINITY;
          if (kt * 64 + 32 + kl > qg) sB[r] = -INFINITY;
        }
      }

      // ---- online softmax (exp2 domain) ----
      float tm[16];
#pragma unroll
      for (int r = 0; r < 16; ++r) tm[r] = fmaxf(sA[r], sB[r]);
#pragma unroll
      for (int s = 8; s >= 1; s >>= 1)
#pragma unroll
        for (int r = 0; r < s; ++r) tm[r] = fmaxf(tm[r], tm[r + s]);
      const float pm = fmaxf(tm[0], __shfl_xor(tm[0], 32));

      if (!__all(pm <= m_r + 11.5416f)) {
        const float mnew = fmaxf(m_r, pm);
        const float corr = fexp2(m_r - mnew);
        l_r *= corr;
#pragma unroll
        for (int r = 0; r < 16; ++r) { oA[r] *= corr; oB[r] *= corr; }
        m_r = mnew;
      }

#pragma unroll
      for (int r = 0; r < 16; ++r) sA[r] = fexp2(sA[r] - m_r);
#pragma unroll
      for (int r = 0; r < 16; ++r) sB[r] = fexp2(sB[r] - m_r);

      float ts[16];
#pragma unroll
      for (int r = 0; r < 16; ++r) ts[r] = sA[r] + sB[r];
#pragma unroll
      for (int s = 8; s >= 1; s >>= 1)
#pragma unroll
        for (int r = 0; r < s; ++r) ts[r] += ts[r + s];
      l_r += ts[0];

      // ---- P^T fragments ----
      bf16x8 pf0 = pk_swap8(sA[0], sA[1], sA[2], sA[3], sA[4], sA[5], sA[6], sA[7]);
      bf16x8 pf1 = pk_swap8(sA[8], sA[9], sA[10], sA[11], sA[12], sA[13], sA[14], sA[15]);
      bf16x8 pf2 = pk_swap8(sB[0], sB[1], sB[2], sB[3], sB[4], sB[5], sB[6], sB[7]);
      bf16x8 pf3 = pk_swap8(sB[8], sB[9], sB[10], sB[11], sB[12], sB[13], sB[14], sB[15]);

      // ---- O^T += mfma(V^T, P^T) ----
      __builtin_amdgcn_s_setprio(1);
#pragma unroll
      for (int c = 0; c < 4; ++c) {
        const int sl = ((2 * c + hi) ^ (qi & 7)) << 3;
        bf16x8 vfA = *(const bf16x8*)&Vs[cur][qi * 64 + sl];
        bf16x8 vfB = *(const bf16x8*)&Vs[cur][(qi + 32) * 64 + sl];
        bf16x8 pf = (c == 0) ? pf0 : (c == 1) ? pf1 : (c == 2) ? pf2 : pf3;
        oA = __builtin_amdgcn_mfma_f32_32x32x16_bf16(vfA, pf, oA, 0, 0, 0);
        oB = __builtin_amdgcn_mfma_f32_32x32x16_bf16(vfB, pf, oB, 0, 0, 0);
      }
      __builtin_amdgcn_s_setprio(0);
    }

    asm volatile("s_waitcnt vmcnt(0)" ::: "memory");  // next-tile loads landed
    __builtin_amdgcn_s_barrier();                     // + all waves' reads done
  }
#undef STAGE_KV

  // ---- epilogue ----
  const float lt = l_r + __shfl_xor(l_r, 32);
  const float inv = lt > 0.f ? 1.f / lt : 0.f;
#pragma unroll
  for (int r = 0; r < 16; ++r) { oA[r] *= inv; oB[r] *= inv; }

  bf16x8 e0 = pk_swap8(oA[0], oA[1], oA[2], oA[3], oA[4], oA[5], oA[6], oA[7]);
  bf16x8 e1 = pk_swap8(oA[8], oA[9], oA[10], oA[11], oA[12], oA[13], oA[14], oA[15]);
  bf16x8 e2 = pk_swap8(oB[0], oB[1], oB[2], oB[3], oB[4], oB[5], oB[6], oB[7]);
  bf16x8 e3 = pk_swap8(oB[8], oB[9], oB[10], oB[11], oB[12], oB[13], oB[14], oB[15]);

  if (lslot < 0) {
    bf16* ob = &out[(size_t)qrow * EMBED + h * HDIM];
    *(bf16x8*)(ob + hi * 8) = e0;
    *(bf16x8*)(ob + 16 + hi * 8) = e1;
    *(bf16x8*)(ob + 32 + hi * 8) = e2;
    *(bf16x8*)(ob + 48 + hi * 8) = e3;
  } else {
    const int gslot = h * 96 + lslot;
    bf16* base = (gslot < 1024)
                     ? (bf16*)((char*)partO_main + (size_t)gslot * 16384)
                     : (bf16*)((char*)partO_ovf + (size_t)(gslot - 1024) * 16384);
    const int lr = w * 32 + qi;
    bf16* pb = base + (size_t)lr * 64;
    *(bf16x8*)(pb + hi * 8) = e0;
    *(bf16x8*)(pb + 16 + hi * 8) = e1;
    *(bf16x8*)(pb + 32 + hi * 8) = e2;
    *(bf16x8*)(pb + 48 + hi * 8) = e3;
    if (hi == 0) partML[gslot * 128 + lr] = make_float2(m_r, lt);
  }
}

// ---------------------------------------------------------------------------
// Merge 2-6 kv-split partials (exp2 domain). Grid (26, HEADS), 256 thr.
// ---------------------------------------------------------------------------
__global__ __launch_bounds__(256) void merge_partials(
    const bf16* __restrict__ partO_main, const bf16* __restrict__ partO_ovf,
    const float2* __restrict__ partML, bf16* __restrict__ out) {
  const int qtb = 6 + blockIdx.x;
  const int h = blockIdx.y;
  int np, lbase;
  if (qtb < 12)      { np = 2; lbase = (qtb - 6) * 2; }
  else if (qtb < 18) { np = 3; lbase = 12 + (qtb - 12) * 3; }
  else if (qtb < 24) { np = 4; lbase = 30 + (qtb - 18) * 4; }
  else if (qtb < 30) { np = 5; lbase = 54 + (qtb - 24) * 5; }
  else               { np = 6; lbase = 84 + (qtb - 30) * 6; }
  const int gbase = h * 96 + lbase;
  const int r = threadIdx.x >> 1;
  const int dh = (threadIdx.x & 1) * 32;

  float mm = -INFINITY;
  float mv[6], lv[6];
#pragma unroll
  for (int p = 0; p < 6; ++p)
    if (p < np) {
      const float2 ml = partML[(gbase + p) * 128 + r];
      mv[p] = ml.x; lv[p] = ml.y;
      mm = fmaxf(mm, ml.x);
    }
  float wsum = 0.f, wgt[6];
#pragma unroll
  for (int p = 0; p < 6; ++p)
    if (p < np) {
      wgt[p] = lv[p] * fexp2(mv[p] - mm);
      wsum += wgt[p];
    }
  const float inv = 1.f / wsum;
#pragma unroll
  for (int p = 0; p < 6; ++p)
    if (p < np) wgt[p] *= inv;

  const bf16* pp[6];
#pragma unroll
  for (int p = 0; p < 6; ++p)
    if (p < np) {
      const int gs = gbase + p;
      const bf16* base = (gs < 1024)
                             ? (const bf16*)((const char*)partO_main + (size_t)gs * 16384)
                             : (const bf16*)((const char*)partO_ovf + (size_t)(gs - 1024) * 16384);
      pp[p] = base + (size_t)r * 64 + dh;
    }

  bf16* ob = &out[(size_t)(qtb * 128 + r) * EMBED + h * HDIM + dh];
#pragma unroll
  for (int c = 0; c < 4; ++c) {
    float acc[8] = {0.f, 0.f, 0.f, 0.f, 0.f, 0.f, 0.f, 0.f};
#pragma unroll
    for (int p = 0; p < 6; ++p)
      if (p < np) {
        bf16x8 v = *(const bf16x8*)(pp[p] + c * 8);
#pragma unroll
        for (int j = 0; j < 8; ++j) acc[j] += wgt[p] * (float)v[j];
      }
    bf16x8 o;
#pragma unroll
    for (int j = 0; j < 8; ++j) o[j] = (bf16)acc[j];
    *(bf16x8*)(ob + c * 8) = o;
  }
}

// ---------------------------------------------------------------------------
extern "C" void kernel_launch(void* const* d_in, const int* in_sizes, int n_in,
                              void* d_out, int out_size, void* d_ws, size_t ws_size,
                              hipStream_t stream) {
  const float* x     = (const float*)d_in[0];
  const float* W_qkv = (const float*)d_in[1];
  const float* b_qkv = (const float*)d_in[2];
  const float* W_out = (const float*)d_in[3];
  const float* b_out = (const float*)d_in[4];
  float* out = (float*)d_out;

  char* ws = (char*)d_ws;
  const size_t MB = 1024 * 1024;
  bf16* x_bf   = (bf16*)(ws + 0);        // 8 MB; dead after QKV gemm
  bf16* WqkvT  = (bf16*)(ws + 8 * MB);   // 6 MB; dead after QKV gemm
  bf16* WoutT  = (bf16*)(ws + 14 * MB);  // 2 MB (live to end)
  bf16* qkvb   = (bf16*)(ws + 16 * MB);  // 24 MB
  bf16* vT     = (bf16*)(ws + 40 * MB);  // 8 MB
  bf16* attn_o = (bf16*)(ws + 48 * MB);  // 8 MB
  // kv-split partials: 1536 slots x 16 KB. 0..1023 in d_out (rewritten by
  // final GEMM), 1024..1535 over dead x_bf. partML over WqkvT.
  bf16*   partO_main = (bf16*)d_out;
  bf16*   partO_ovf  = (bf16*)(ws + 0);
  float2* partML     = (float2*)(ws + 8 * MB);

  f32_to_bf16<<<(T_SEQ * EMBED) / (256 * 8), 256, 0, stream>>>(x, x_bf, T_SEQ * EMBED);
  transpose_f32_bf16<<<dim3(3 * EMBED / 32, EMBED / 32), 256, 0, stream>>>(
      W_qkv, WqkvT, EMBED, 3 * EMBED);
  transpose_f32_bf16<<<dim3(EMBED / 32, EMBED / 32), 256, 0, stream>>>(
      W_out, WoutT, EMBED, EMBED);

  gemm_bt_bias<false><<<dim3(3 * EMBED / 128, T_SEQ / 128), 256, 0, stream>>>(
      x_bf, WqkvT, b_qkv, qkvb, T_SEQ, 3 * EMBED, EMBED);

  transpose_v<<<dim3(T_SEQ / 64, HEADS), 256, 0, stream>>>(qkvb, vT);

  flash_attn_mfma<<<dim3(102 * HEADS), 256, 0, stream>>>(qkvb, vT, attn_o, partO_main,
                                                         partO_ovf, partML);
  merge_partials<<<dim3(26, HEADS), 256, 0, stream>>>(partO_main, partO_ovf, partML,
                                                      attn_o);

  gemm_bt_bias<true><<<dim3(EMBED / 128, T_SEQ / 128), 256, 0, stream>>>(
      attn_o, WoutT, b_out, out, T_SEQ, EMBED, EMBED);
}